// Round 3
// baseline (19643.565 us; speedup 1.0000x reference)
//
#include <hip/hip_runtime.h>
#include <hip/hip_bf16.h>
#include <stdint.h>

typedef __hip_bfloat16 bf16;

#define CONV_BS 1024

__device__ __forceinline__ float b2f(bf16 x) { return __bfloat162float(x); }
__device__ __forceinline__ bf16  f2b(float x) { return __float2bfloat16(x); }

// ---------------------------------------------------------------------------
// Top-k: exact rank selection with jax tie-breaking (lower index wins).
// key = (monotone-mapped value, 4095-idx) as u64, rank = #{keys > mine}.
// rank is unique per batch -> sel slot = rank (no atomics needed).
// ---------------------------------------------------------------------------
__global__ __launch_bounds__(1024) void topk_kernel(const float* __restrict__ err,
                                                    float* __restrict__ ref_out,
                                                    int* __restrict__ sel)
{
    __shared__ uint64_t keys[4096];
    const int b = blockIdx.x, t = threadIdx.x;
    const float* e = err + b * 4096;
    float v[4]; uint64_t k[4];
#pragma unroll
    for (int q = 0; q < 4; ++q) {
        int idx = t + q * 1024;
        float val = e[idx];
        v[q] = val;
        uint32_t u = __float_as_uint(val);
        u ^= (u >> 31) ? 0xFFFFFFFFu : 0x80000000u;   // monotone float->uint
        k[q] = ((uint64_t)u << 32) | (uint32_t)(4095 - idx);
        keys[idx] = k[q];
    }
    __syncthreads();
    int r[4] = {0, 0, 0, 0};
#pragma unroll 8
    for (int j = 0; j < 4096; ++j) {
        uint64_t kj = keys[j];
#pragma unroll
        for (int q = 0; q < 4; ++q) r[q] += (kj > k[q]) ? 1 : 0;
    }
#pragma unroll
    for (int q = 0; q < 4; ++q) {
        int idx = t + q * 1024;
        bool s = (r[q] < 512);
        if (s) sel[b * 512 + r[q]] = idx;
        ref_out[b * 4096 + idx] = (s && v[q] > 0.f) ? 1.f : 0.f;
    }
}

// ---------------------------------------------------------------------------
// Weight transpose to [ci][tap][co] f32 (inner loop loads 8 contiguous f32 of
// consecutive co per (ci,tap)).
// ---------------------------------------------------------------------------
__global__ void wt_kernel(const float* __restrict__ w0,
                          const float* __restrict__ wpre,
                          const float* __restrict__ wpost,
                          float* __restrict__ w0T,
                          float* __restrict__ preT,
                          float* __restrict__ postT)
{
    int t = blockIdx.x * blockDim.x + threadIdx.x;
    if (t < 22320) {                       // w0: (80,31,3,3) -> [ci31][tap9][co80]
        int ci = t / 720, r = t % 720, tap = r / 80, co = r % 80;
        w0T[t] = w0[(co * 31 + ci) * 9 + tap];
    }
    int t2 = t - 22320;
    if (t2 >= 0 && t2 < 172800) {          // w_pre: (3,80,80,3,3)
        int l = t2 / 57600, d = t2 % 57600;
        int ci = d / 720, r = d % 720, tap = r / 80, co = r % 80;
        preT[t2] = wpre[((l * 80 + co) * 80 + ci) * 9 + tap];
    }
    int t3 = t - 195120;
    if (t3 >= 0 && t3 < 403200) {          // w_post: (7,80,80,3,3)
        int l = t3 / 57600, d = t3 % 57600;
        int ci = d / 720, r = d % 720, tap = r / 80, co = r % 80;
        postT[t3] = wpost[((l * 80 + co) * 80 + ci) * 9 + tap];
    }
}

// ---------------------------------------------------------------------------
__global__ void copy_kernel(const uint4* __restrict__ src, uint4* __restrict__ dst, int n)
{
    int t = blockIdx.x * blockDim.x + threadIdx.x;
    if (t < n) dst[t] = src[t];
}

// ---------------------------------------------------------------------------
// VALID 3x3 conv + BN + ReLU from bf16 LDS input; f32 accumulate.
// F32OUT=true for the layer feeding the f32 residual trunk.
// ---------------------------------------------------------------------------
template <bool F32OUT>
__device__ void conv_valid(const bf16* __restrict__ in, int C_in, int n_in,
                           void* __restrict__ outv,
                           const float* __restrict__ wT,
                           const float* __restrict__ bnp,
                           float* s_inv, float* s_beta)
{
    const int tid = threadIdx.x;
    __syncthreads();
    if (tid < 80) {
        float g = bnp[tid], bb = bnp[80 + tid];
        float m = bnp[160 + tid], vv = bnp[240 + tid];
        float inv = g * rsqrtf(vv + 1e-5f);
        s_inv[tid] = inv; s_beta[tid] = bb - m * inv;
    }
    __syncthreads();
    const int n_out = n_in - 2, npix = n_out * n_out;
    for (int item = tid; item < 10 * npix; item += CONV_BS) {
        int cb = item / npix, pix = item - cb * npix;
        int y = pix / n_out, x = pix - y * n_out;
        float acc[8] = {0, 0, 0, 0, 0, 0, 0, 0};
        const float* wp = wT + cb * 8;
        const bf16* ib = in + y * n_in + x;
        for (int ci = 0; ci < C_in; ++ci) {
            const bf16* ibc = ib + ci * n_in * n_in;
            const float* wc = wp + ci * 720;
#pragma unroll
            for (int dy = 0; dy < 3; ++dy)
#pragma unroll
            for (int dx = 0; dx < 3; ++dx) {
                float a = b2f(ibc[dy * n_in + dx]);
                const float4* w4 = (const float4*)(wc + (dy * 3 + dx) * 80);
                float4 wa = w4[0], wb = w4[1];
                acc[0] += a * wa.x; acc[1] += a * wa.y;
                acc[2] += a * wa.z; acc[3] += a * wa.w;
                acc[4] += a * wb.x; acc[5] += a * wb.y;
                acc[6] += a * wb.z; acc[7] += a * wb.w;
            }
        }
        int cb8 = cb * 8;
#pragma unroll
        for (int kk = 0; kk < 8; ++kk) {
            float o = fmaxf(acc[kk] * s_inv[cb8 + kk] + s_beta[cb8 + kk], 0.f);
            if (F32OUT) ((float*)outv)[(cb8 + kk) * npix + pix] = o;
            else        ((bf16*)outv)[(cb8 + kk) * npix + pix] = f2b(o);
        }
    }
}

// SAME 3x3 conv + BN + ReLU from f32 16x16 trunk -> bf16 branch buffer Z.
__device__ void conv_same_post(const float* __restrict__ Y, bf16* __restrict__ Z,
                               const float* __restrict__ wT,
                               const float* __restrict__ bnp,
                               float* s_inv, float* s_beta)
{
    const int tid = threadIdx.x;
    __syncthreads();
    if (tid < 80) {
        float g = bnp[tid], bb = bnp[80 + tid];
        float m = bnp[160 + tid], vv = bnp[240 + tid];
        float inv = g * rsqrtf(vv + 1e-5f);
        s_inv[tid] = inv; s_beta[tid] = bb - m * inv;
    }
    __syncthreads();
    for (int item = tid; item < 10 * 256; item += CONV_BS) {
        int cb = item >> 8, pix = item & 255;
        int y = pix >> 4, x = pix & 15;
        float acc[8] = {0, 0, 0, 0, 0, 0, 0, 0};
        const float* wp = wT + cb * 8;
        for (int ci = 0; ci < 80; ++ci) {
            const float* yc = Y + ci * 256;
            const float* wc = wp + ci * 720;
#pragma unroll
            for (int dy = 0; dy < 3; ++dy) {
                int iy = y + dy - 1;
                if ((unsigned)iy >= 16u) continue;
#pragma unroll
                for (int dx = 0; dx < 3; ++dx) {
                    int ix = x + dx - 1;
                    if ((unsigned)ix >= 16u) continue;
                    float a = yc[iy * 16 + ix];
                    const float4* w4 = (const float4*)(wc + (dy * 3 + dx) * 80);
                    float4 wa = w4[0], wb = w4[1];
                    acc[0] += a * wa.x; acc[1] += a * wa.y;
                    acc[2] += a * wa.z; acc[3] += a * wa.w;
                    acc[4] += a * wb.x; acc[5] += a * wb.y;
                    acc[6] += a * wb.z; acc[7] += a * wb.w;
                }
            }
        }
        int cb8 = cb * 8;
#pragma unroll
        for (int kk = 0; kk < 8; ++kk) {
            float o = fmaxf(acc[kk] * s_inv[cb8 + kk] + s_beta[cb8 + kk], 0.f);
            Z[(cb8 + kk) * 256 + pix] = f2b(o);
        }
    }
    __syncthreads();
}

// ---------------------------------------------------------------------------
// One block = one patch. All activations LDS-resident.
// LDS layout (byte offsets in smem[141440]):
//   X  bf16 31x24x24   @ 0      (35712)      conv0 input
//   A0 bf16 80x22x22   @ 64000  (77440)      <- peak concurrency A0+A1=141440
//   A1 bf16 80x20x20   @ 0      (64000)
//   A2 bf16 80x18x18   @ 89600  (51840)
//   Y  f32  80x16x16   @ 0      (81920)      residual trunk, f32 for accuracy
//   Z  bf16 80x16x16   @ 100480 (40960)      post-branch temp
// ---------------------------------------------------------------------------
__global__ __launch_bounds__(1024) void refine_kernel(
    const int* __restrict__ sel,
    const float* __restrict__ hid, const float* __restrict__ pha,
    const float* __restrict__ w0T, const float* __restrict__ preT,
    const float* __restrict__ postT, const float* __restrict__ w_last,
    const float* __restrict__ bn0, const float* __restrict__ bn_pre,
    const float* __restrict__ bn_post,
    float* __restrict__ out)
{
    __shared__ __align__(16) char smem[141440];
    __shared__ float s_inv[80], s_beta[80];
    bf16*  X  = (bf16*)(smem);
    bf16*  A0 = (bf16*)(smem + 64000);
    bf16*  A1 = (bf16*)(smem);
    bf16*  A2 = (bf16*)(smem + 89600);
    float* Y  = (float*)(smem);
    bf16*  Z  = (bf16*)(smem + 100480);

    const int tid = threadIdx.x;
    const int p = blockIdx.x;
    const int e = sel[p];
    const int b = p >> 9;
    const int pi = e >> 6, pj = e & 63;

    // ---- gather 31x24x24 window (zero-padded at image borders) ----
    const int r0 = pi * 16 - 4, c0 = pj * 16 - 4;
    for (int t = tid; t < 31 * 576; t += CONV_BS) {
        int c = t / 576, rem = t % 576, r = rem / 24, cc = rem % 24;
        int gr = r0 + r, gc = c0 + cc;
        float val = 0.f;
        if ((unsigned)gr < 1024u && (unsigned)gc < 1024u) {
            val = (c < 30) ? hid[((b * 30 + c) * 1024 + gr) * 1024 + gc]
                           : pha[(b * 1024 + gr) * 1024 + gc];
        }
        X[t] = f2b(val);
    }

    // ---- conv0 + 3 pre layers (VALID) ----
    conv_valid<false>(X,  31, 24, A0, w0T,           bn0,          s_inv, s_beta);
    conv_valid<false>(A0, 80, 22, A1, preT,          bn_pre,       s_inv, s_beta);
    conv_valid<false>(A1, 80, 20, A2, preT + 57600,  bn_pre + 320, s_inv, s_beta);
    conv_valid<true >(A2, 80, 18, Y,  preT + 115200, bn_pre + 640, s_inv, s_beta);

    // ---- 7 residual post layers (SAME) ----
    for (int l = 0; l < 7; ++l) {
        conv_same_post(Y, Z, postT + l * 57600, bn_post + l * 320, s_inv, s_beta);
        for (int t = tid; t < 80 * 256; t += CONV_BS) Y[t] += b2f(Z[t]);
        __syncthreads();
    }

    // ---- last conv 80 -> 1 (SAME), scatter into output image ----
    __syncthreads();
    if (tid < 256) {
        int y = tid >> 4, x = tid & 15;
        float acc = 0.f;
        for (int ci = 0; ci < 80; ++ci) {
            const float* yc = Y + ci * 256;
#pragma unroll
            for (int dy = 0; dy < 3; ++dy) {
                int iy = y + dy - 1;
                if ((unsigned)iy >= 16u) continue;
#pragma unroll
                for (int dx = 0; dx < 3; ++dx) {
                    int ix = x + dx - 1;
                    if ((unsigned)ix >= 16u) continue;
                    acc += yc[iy * 16 + ix] * w_last[ci * 9 + dy * 3 + dx];
                }
            }
        }
        out[b * 1048576 + (pi * 16 + y) * 1024 + (pj * 16 + x)] = acc;
    }
}

// ---------------------------------------------------------------------------
extern "C" void kernel_launch(void* const* d_in, const int* in_sizes, int n_in,
                              void* d_out, int out_size, void* d_ws, size_t ws_size,
                              hipStream_t stream)
{
    (void)in_sizes; (void)n_in; (void)out_size; (void)ws_size;
    const float* pha     = (const float*)d_in[0];
    const float* err     = (const float*)d_in[1];
    const float* hid     = (const float*)d_in[2];
    const float* w0      = (const float*)d_in[3];
    const float* bn0     = (const float*)d_in[4];
    const float* w_pre   = (const float*)d_in[5];
    const float* bn_pre  = (const float*)d_in[6];
    const float* w_post  = (const float*)d_in[7];
    const float* bn_post = (const float*)d_in[8];
    const float* w_last  = (const float*)d_in[9];
    float* out = (float*)d_out;

    char* ws = (char*)d_ws;
    int* sel     = (int*)(ws + 64);        // 1024 selected flat indices
    float* w0T   = (float*)(ws + 8192);    // 22320 f32
    float* preT  = (float*)(ws + 98304);   // 3*57600 f32
    float* postT = (float*)(ws + 790528);  // 7*57600 f32  (ws use ~2.4 MB)

    hipLaunchKernelGGL(wt_kernel, dim3(2338), dim3(256), 0, stream,
                       w0, w_pre, w_post, w0T, preT, postT);
    hipLaunchKernelGGL(topk_kernel, dim3(2), dim3(1024), 0, stream,
                       err, out + 2097152, sel);
    hipLaunchKernelGGL(copy_kernel, dim3(2048), dim3(256), 0, stream,
                       (const uint4*)pha, (uint4*)out, 524288);
    hipLaunchKernelGGL(refine_kernel, dim3(1024), dim3(CONV_BS), 0, stream,
                       sel, hid, pha, w0T, preT, postT, w_last,
                       bn0, bn_pre, bn_post, out);
}

// Round 4
// 1065.646 us; speedup vs baseline: 18.4335x; 18.4335x over previous
//
#include <hip/hip_runtime.h>
#include <hip/hip_bf16.h>
#include <stdint.h>

typedef __hip_bfloat16 bf16;
typedef __attribute__((ext_vector_type(8))) short short8;
typedef __attribute__((ext_vector_type(4))) float f32x4;

__device__ __forceinline__ float b2f(bf16 x) { return __bfloat162float(x); }
__device__ __forceinline__ bf16  f2b(float x) { return __float2bfloat16(x); }

#define NW 8          // waves per block
// LDS layout (bytes). Peak phase: A0+A1+Bt = 77440+64000+16640 = 158080.
#define BT_OFF  0        // 16640  B-tap buffer [80][104] bf16
#define X_OFF   16640    // 36864  conv0 input [576][32] bf16
#define A0_OFF  80640    // 77440  [484][80] bf16
#define A1_OFF  16640    // 64000  [400][80] bf16
#define A2_OFF  106240   // 51840  [324][80] bf16
#define Y_OFF   16640    // 86016  [256][84] f32 trunk (padded stride)
#define Z_OFF   106240   // 40960  [256][80] bf16 trunk mirror (A operand)
#define SMEM_SZ 158080

// ---------------------------------------------------------------------------
// Top-k: exact rank selection with jax tie-breaking (lower index wins).
// ---------------------------------------------------------------------------
__global__ __launch_bounds__(1024) void topk_kernel(const float* __restrict__ err,
                                                    float* __restrict__ ref_out,
                                                    int* __restrict__ sel)
{
    __shared__ uint64_t keys[4096];
    const int b = blockIdx.x, t = threadIdx.x;
    const float* e = err + b * 4096;
    float v[4]; uint64_t k[4];
#pragma unroll
    for (int q = 0; q < 4; ++q) {
        int idx = t + q * 1024;
        float val = e[idx];
        v[q] = val;
        uint32_t u = __float_as_uint(val);
        u ^= (u >> 31) ? 0xFFFFFFFFu : 0x80000000u;
        k[q] = ((uint64_t)u << 32) | (uint32_t)(4095 - idx);
        keys[idx] = k[q];
    }
    __syncthreads();
    int r[4] = {0, 0, 0, 0};
#pragma unroll 8
    for (int j = 0; j < 4096; ++j) {
        uint64_t kj = keys[j];
#pragma unroll
        for (int q = 0; q < 4; ++q) r[q] += (kj > k[q]) ? 1 : 0;
    }
#pragma unroll
    for (int q = 0; q < 4; ++q) {
        int idx = t + q * 1024;
        bool s = (r[q] < 512);
        if (s) sel[b * 512 + r[q]] = idx;
        ref_out[b * 4096 + idx] = (s && v[q] > 0.f) ? 1.f : 0.f;
    }
}

// ---------------------------------------------------------------------------
// Weight prepack:
//  W[l][tap][co][kp=104] bf16, k-tail zero (l0: ci<31, else ci<80)
//  wlastT[tap][ci] f32; bnprep[l][co][{inv,beta}] f32
// ---------------------------------------------------------------------------
__global__ void wt_kernel(const float* __restrict__ w0, const float* __restrict__ wpre,
                          const float* __restrict__ wpost, const float* __restrict__ w_last,
                          const float* __restrict__ bn0, const float* __restrict__ bn_pre,
                          const float* __restrict__ bn_post,
                          bf16* __restrict__ W, float* __restrict__ wlastT,
                          float* __restrict__ bnprep)
{
    int t = blockIdx.x * blockDim.x + threadIdx.x;
    if (t < 823680) {
        int kp = t % 104;
        int co = (t / 104) % 80;
        int tap = (t / 8320) % 9;
        int l = t / 74880;
        float v = 0.f;
        if (l == 0)      { if (kp < 31) v = w0[(co * 31 + kp) * 9 + tap]; }
        else if (l <= 3) { if (kp < 80) v = wpre[(((l - 1) * 80 + co) * 80 + kp) * 9 + tap]; }
        else             { if (kp < 80) v = wpost[(((l - 4) * 80 + co) * 80 + kp) * 9 + tap]; }
        W[t] = f2b(v);
    } else if (t < 824400) {
        int i = t - 823680; int tap = i / 80, ci = i % 80;
        wlastT[tap * 80 + ci] = w_last[ci * 9 + tap];
    } else if (t < 825280) {
        int i = t - 824400; int l = i / 80, co = i % 80;
        const float* src = (l == 0) ? bn0 : (l <= 3 ? bn_pre + (l - 1) * 320
                                                    : bn_post + (l - 4) * 320);
        float g = src[co], bb = src[80 + co], m = src[160 + co], vv = src[240 + co];
        float inv = g * rsqrtf(vv + 1e-5f);
        bnprep[(l * 80 + co) * 2]     = inv;
        bnprep[(l * 80 + co) * 2 + 1] = bb - m * inv;
    }
}

// ---------------------------------------------------------------------------
__global__ void copy_kernel(const uint4* __restrict__ src, uint4* __restrict__ dst, int n)
{
    int t = blockIdx.x * blockDim.x + threadIdx.x;
    if (t < n) dst[t] = src[t];
}

// ---------------------------------------------------------------------------
// One 3x3 conv layer as 9 tap-GEMMs on mfma_f32_16x16x32_bf16.
// A: LDS channel-last [pix][SLOTS] bf16 @ inOff. B: staged per tap @ BT_OFF.
// MODE 0: bf16 out @ outOff [pix][80]; MODE 1: f32 -> Y and bf16 -> Z (pre3);
// MODE 2: residual trunk update Y += relu(bn(conv)), Z = bf16(Y).
// ---------------------------------------------------------------------------
template <int NIN, int NOUT, int SLOTS, int KB, bool SAMEP, int MODE>
__device__ void conv_mfma(char* sm, int inOff, int outOff,
                          const bf16* __restrict__ Wl, const float* __restrict__ bnl)
{
    const int tid = threadIdx.x;
    const int wv = tid >> 6, lane = tid & 63;
    const int r = lane & 15, kg = lane >> 4;
    constexpr int NPIX = NOUT * NOUT;
    constexpr int NMT = (NPIX + 15) / 16;
    constexpr int NPAIR = (NMT + 1) / 2;
    constexpr int PMAX = (NPAIR > NW) ? 2 : 1;
    constexpr int SSTR = SLOTS * 2;

    // per-(pair,mtile) A-row coords (lane row = lane&15)
    int ay[PMAX][2], ax[PMAX][2];
    bool act[PMAX][2];
#pragma unroll
    for (int pp = 0; pp < PMAX; ++pp)
#pragma unroll
        for (int mm = 0; mm < 2; ++mm) {
            int mt = (wv + pp * NW) * 2 + mm;
            int pix = mt * 16 + r;
            act[pp][mm] = (mt < NMT);
            int cp = pix < NPIX ? pix : NPIX - 1;
            ay[pp][mm] = cp / NOUT;
            ax[pp][mm] = cp % NOUT;
        }

    f32x4 zz = {0.f, 0.f, 0.f, 0.f};
    f32x4 acc[PMAX][2][5];
#pragma unroll
    for (int pp = 0; pp < PMAX; ++pp)
#pragma unroll
        for (int mm = 0; mm < 2; ++mm)
#pragma unroll
            for (int n = 0; n < 5; ++n) acc[pp][mm][n] = zz;

    for (int tap = 0; tap < 9; ++tap) {
        __syncthreads();   // previous tap's reads (and prior-phase writes) done
        {   // stage B_tap: 16640 B
            const uint4* src = (const uint4*)(Wl + tap * 8320);
            uint4* dst = (uint4*)(sm + BT_OFF);
            for (int i = tid; i < 1040; i += 512) dst[i] = src[i];
        }
        __syncthreads();
        const int dy = tap / 3, dx = tap % 3;
#pragma unroll
        for (int kb = 0; kb < KB; ++kb) {
            short8 bf[5];
#pragma unroll
            for (int n = 0; n < 5; ++n)
                bf[n] = *(const short8*)(sm + BT_OFF + (n * 16 + r) * 208 + kb * 64 + kg * 16);
#pragma unroll
            for (int pp = 0; pp < PMAX; ++pp) {
                int pairIdx = wv + pp * NW;
                if (pairIdx * 2 >= NMT) continue;
#pragma unroll
                for (int mm = 0; mm < 2; ++mm) {
                    int iy = ay[pp][mm] + dy - (SAMEP ? 1 : 0);
                    int ix = ax[pp][mm] + dx - (SAMEP ? 1 : 0);
                    bool ok = act[pp][mm];
                    if (SAMEP) ok = ok && (unsigned)iy < (unsigned)NIN && (unsigned)ix < (unsigned)NIN;
                    if (KB == 3 && kb == 2 && lane >= 32) ok = false;  // k >= 80 tail
                    short8 af = {0, 0, 0, 0, 0, 0, 0, 0};
                    if (ok)
                        af = *(const short8*)(sm + inOff + (iy * NIN + ix) * SSTR + kb * 64 + kg * 16);
#pragma unroll
                    for (int n = 0; n < 5; ++n)
                        acc[pp][mm][n] = __builtin_amdgcn_mfma_f32_16x16x32_bf16(
                            af, bf[n], acc[pp][mm][n], 0, 0, 0);
                }
            }
        }
    }

    // BN params per ntile (store-time col = lane&15)
    float invb[5], betb[5];
#pragma unroll
    for (int n = 0; n < 5; ++n) {
        float2 v = ((const float2*)bnl)[n * 16 + r];
        invb[n] = v.x; betb[n] = v.y;
    }

    if (MODE == 2) __syncthreads();   // K-loop reads of Z (other waves' pixels) must finish

#pragma unroll
    for (int pp = 0; pp < PMAX; ++pp) {
        int pairIdx = wv + pp * NW;
#pragma unroll
        for (int mm = 0; mm < 2; ++mm) {
            int mt = pairIdx * 2 + mm;
#pragma unroll
            for (int n = 0; n < 5; ++n) {
                int co = n * 16 + r;
#pragma unroll
                for (int j = 0; j < 4; ++j) {
                    int pix = mt * 16 + kg * 4 + j;
                    if (mt < NMT && pix < NPIX) {
                        float o = fmaxf(acc[pp][mm][n][j] * invb[n] + betb[n], 0.f);
                        if (MODE == 0) {
                            *(bf16*)(sm + outOff + pix * 160 + co * 2) = f2b(o);
                        } else if (MODE == 1) {
                            *(float*)(sm + Y_OFF + pix * 336 + co * 4) = o;
                        } else {
                            float* yp = (float*)(sm + Y_OFF + pix * 336 + co * 4);
                            float nv = *yp + o;
                            *yp = nv;
                            *(bf16*)(sm + Z_OFF + pix * 160 + co * 2) = f2b(nv);
                        }
                    }
                }
            }
        }
    }

    if (MODE == 1) {   // Z overlaps A2: write only after all waves leave A2
        __syncthreads();
#pragma unroll
        for (int pp = 0; pp < PMAX; ++pp) {
            int pairIdx = wv + pp * NW;
#pragma unroll
            for (int mm = 0; mm < 2; ++mm) {
                int mt = pairIdx * 2 + mm;
#pragma unroll
                for (int n = 0; n < 5; ++n) {
                    int co = n * 16 + r;
#pragma unroll
                    for (int j = 0; j < 4; ++j) {
                        int pix = mt * 16 + kg * 4 + j;
                        if (mt < NMT && pix < NPIX) {
                            float o = fmaxf(acc[pp][mm][n][j] * invb[n] + betb[n], 0.f);
                            *(bf16*)(sm + Z_OFF + pix * 160 + co * 2) = f2b(o);
                        }
                    }
                }
            }
        }
    }
}

// ---------------------------------------------------------------------------
__global__ __launch_bounds__(512, 2) void refine_kernel(
    const int* __restrict__ sel,
    const float* __restrict__ hid, const float* __restrict__ pha,
    const bf16* __restrict__ W, const float* __restrict__ wlastT,
    const float* __restrict__ bnprep, float* __restrict__ out)
{
    __shared__ __align__(16) char sm[SMEM_SZ];
    const int tid = threadIdx.x;
    const int p = blockIdx.x;
    const int e = sel[p];
    const int b = p >> 9;
    const int pi = e >> 6, pj = e & 63;

    // ---- gather: X[pix 24x24][32] bf16 channel-last, slot31 & OOB = 0 ----
    const int r0 = pi * 16 - 4, c0 = pj * 16 - 4;
    bf16* X = (bf16*)(sm + X_OFF);
    for (int t = tid; t < 576 * 32; t += 512) {
        int pix = t >> 5, c = t & 31;
        int gr = r0 + (pix / 24), gc = c0 + (pix % 24);
        float v = 0.f;
        if (c < 31 && (unsigned)gr < 1024u && (unsigned)gc < 1024u)
            v = (c < 30) ? hid[((b * 30 + c) * 1024 + gr) * 1024 + gc]
                         : pha[(b * 1024 + gr) * 1024 + gc];
        X[t] = f2b(v);
    }
    // conv_mfma's first __syncthreads() covers the gather.

    conv_mfma<24, 22, 32, 1, false, 0>(sm, X_OFF,  A0_OFF, W,              bnprep);
    conv_mfma<22, 20, 80, 3, false, 0>(sm, A0_OFF, A1_OFF, W + 1 * 74880, bnprep + 160);
    conv_mfma<20, 18, 80, 3, false, 0>(sm, A1_OFF, A2_OFF, W + 2 * 74880, bnprep + 320);
    conv_mfma<18, 16, 80, 3, false, 1>(sm, A2_OFF, 0,      W + 3 * 74880, bnprep + 480);
    for (int l = 0; l < 7; ++l)
        conv_mfma<16, 16, 80, 3, true, 2>(sm, Z_OFF, 0, W + (4 + l) * 74880,
                                          bnprep + 640 + l * 160);

    // ---- last conv 80->1 SAME from f32 trunk; scatter to output ----
    __syncthreads();
    if (tid < 256) {
        int y = tid >> 4, x = tid & 15;
        float accv = 0.f;
        const float* Yb = (const float*)(sm + Y_OFF);
#pragma unroll
        for (int tap = 0; tap < 9; ++tap) {
            int iy = y + tap / 3 - 1, ix = x + tap % 3 - 1;
            if ((unsigned)iy >= 16u || (unsigned)ix >= 16u) continue;
            const float* yp = Yb + (iy * 16 + ix) * 84;
            const float* wp = wlastT + tap * 80;
            for (int c = 0; c < 80; c += 4) {
                float4 a = *(const float4*)(yp + c);
                float4 wv4 = *(const float4*)(wp + c);
                accv += a.x * wv4.x + a.y * wv4.y + a.z * wv4.z + a.w * wv4.w;
            }
        }
        out[b * 1048576 + (pi * 16 + y) * 1024 + pj * 16 + x] = accv;
    }
}

// ---------------------------------------------------------------------------
extern "C" void kernel_launch(void* const* d_in, const int* in_sizes, int n_in,
                              void* d_out, int out_size, void* d_ws, size_t ws_size,
                              hipStream_t stream)
{
    (void)in_sizes; (void)n_in; (void)out_size; (void)ws_size;
    const float* pha     = (const float*)d_in[0];
    const float* err     = (const float*)d_in[1];
    const float* hid     = (const float*)d_in[2];
    const float* w0      = (const float*)d_in[3];
    const float* bn0     = (const float*)d_in[4];
    const float* w_pre   = (const float*)d_in[5];
    const float* bn_pre  = (const float*)d_in[6];
    const float* w_post  = (const float*)d_in[7];
    const float* bn_post = (const float*)d_in[8];
    const float* w_last  = (const float*)d_in[9];
    float* out = (float*)d_out;

    char* ws = (char*)d_ws;
    bf16*  W      = (bf16*)ws;                    // 823680 bf16 = 1,647,360 B
    float* wlastT = (float*)(ws + 1647360);       // 720 f32
    float* bnprep = (float*)(ws + 1650240);       // 1760 f32
    int*   sel    = (int*)(ws + 1657344);         // 1024 int

    hipLaunchKernelGGL(wt_kernel, dim3(3224), dim3(256), 0, stream,
                       w0, w_pre, w_post, w_last, bn0, bn_pre, bn_post,
                       W, wlastT, bnprep);
    hipLaunchKernelGGL(topk_kernel, dim3(2), dim3(1024), 0, stream,
                       err, out + 2097152, sel);
    hipLaunchKernelGGL(copy_kernel, dim3(2048), dim3(256), 0, stream,
                       (const uint4*)pha, (uint4*)out, 524288);
    hipLaunchKernelGGL(refine_kernel, dim3(1024), dim3(512), 0, stream,
                       sel, hid, pha, W, wlastT, bnprep, out);
}

// Round 5
// 690.629 us; speedup vs baseline: 28.4430x; 1.5430x over previous
//
#include <hip/hip_runtime.h>
#include <hip/hip_bf16.h>
#include <stdint.h>

typedef __hip_bfloat16 bf16;
typedef __attribute__((ext_vector_type(8))) short short8;
typedef __attribute__((ext_vector_type(4))) float f32x4;

__device__ __forceinline__ float b2f(bf16 x) { return __bfloat162float(x); }
__device__ __forceinline__ bf16  f2b(float x) { return __float2bfloat16(x); }

#define NW 8   // waves per block

// LDS layout (bytes), strides padded for 2-way-max bank conflicts:
//   X  [576][112B]  @ 85184..149696   (conv0 input, 32 ch slots used)
//   A0 [484][176B]  @ 0..85184
//   A1 [400][176B]  @ 85184..155584   (over X)
//   A2 [324][176B]  @ 0..57024        (over A0)
//   Y  [256][336B]  @ 57024..143040   f32 trunk
//   Z  [256][176B]  @ 0..45056        bf16 trunk mirror (over A2)
#define X_OFF   85184
#define A0_OFF  0
#define A1_OFF  85184
#define A2_OFF  0
#define Y_OFF   57024
#define Z_OFF   0
#define SMEM_SZ 155584

// ---------------------------------------------------------------------------
// Top-k: exact rank, jax tie-break (lower index wins). 32 blocks:
// blockIdx>>4 = batch, &15 = 256-candidate slice. 4 threads per candidate.
// ---------------------------------------------------------------------------
__global__ __launch_bounds__(1024) void topk_kernel(const float* __restrict__ err,
                                                    float* __restrict__ ref_out,
                                                    int* __restrict__ sel)
{
    __shared__ uint64_t keys[4096];
    const int b = blockIdx.x >> 4, slice = blockIdx.x & 15;
    const float* e = err + b * 4096;
    for (int t = threadIdx.x; t < 4096; t += 1024) {
        uint32_t u = __float_as_uint(e[t]);
        u ^= (u >> 31) ? 0xFFFFFFFFu : 0x80000000u;
        keys[t] = ((uint64_t)u << 32) | (uint32_t)(4095 - t);
    }
    __syncthreads();
    const int cand = slice * 256 + (threadIdx.x >> 2);
    const int part = threadIdx.x & 3;
    const uint64_t mykey = keys[cand];
    int r = 0;
#pragma unroll 8
    for (int j = part * 1024; j < part * 1024 + 1024; ++j)
        r += (keys[j] > mykey) ? 1 : 0;
    r += __shfl_xor(r, 1);
    r += __shfl_xor(r, 2);
    if (part == 0) {
        bool s = (r < 512);
        if (s) sel[b * 512 + r] = cand;
        ref_out[b * 4096 + cand] = (s && e[cand] > 0.f) ? 1.f : 0.f;
    }
}

// ---------------------------------------------------------------------------
// Weight prepack into MFMA-fragment-contiguous layout:
//   Wf[l][tap][kb][n][lane64][8] bf16;  co=n*16+(lane&15), k=kb*32+(lane>>4)*8+i
//   zero for k >= C_in(l).  Plus wlastT[tap][ci] f32, bnprep[l][co][{inv,beta}].
// ---------------------------------------------------------------------------
__global__ void wt_kernel(const float* __restrict__ w0, const float* __restrict__ wpre,
                          const float* __restrict__ wpost, const float* __restrict__ w_last,
                          const float* __restrict__ bn0, const float* __restrict__ bn_pre,
                          const float* __restrict__ bn_post,
                          bf16* __restrict__ Wf, float* __restrict__ wlastT,
                          float* __restrict__ bnprep)
{
    int t = blockIdx.x * blockDim.x + threadIdx.x;
    if (t < 760320) {
        int i = t & 7, lane = (t >> 3) & 63;
        int n = (t >> 9) % 5, kb = (t / 2560) % 3, tap = (t / 7680) % 9, l = t / 69120;
        int co = n * 16 + (lane & 15);
        int k  = kb * 32 + (lane >> 4) * 8 + i;
        int cin = (l == 0) ? 31 : 80;
        float v = 0.f;
        if (k < cin) {
            if (l == 0)      v = w0[(co * 31 + k) * 9 + tap];
            else if (l <= 3) v = wpre[(((l - 1) * 80 + co) * 80 + k) * 9 + tap];
            else             v = wpost[(((l - 4) * 80 + co) * 80 + k) * 9 + tap];
        }
        Wf[t] = f2b(v);
    } else if (t < 761040) {
        int i = t - 760320; int tap = i / 80, ci = i % 80;
        wlastT[tap * 80 + ci] = w_last[ci * 9 + tap];
    } else if (t < 762800) {
        int i = (t - 761040) >> 1;
        int l = i / 80, co = i % 80;
        const float* src = (l == 0) ? bn0 : (l <= 3 ? bn_pre + (l - 1) * 320
                                                    : bn_post + (l - 4) * 320);
        float g = src[co], bb = src[80 + co], m = src[160 + co], vv = src[240 + co];
        float inv = g * rsqrtf(vv + 1e-5f);
        if (t & 1) bnprep[i * 2 + 1] = bb - m * inv;
        else       bnprep[i * 2]     = inv;
    }
}

// ---------------------------------------------------------------------------
__global__ void copy_kernel(const uint4* __restrict__ src, uint4* __restrict__ dst, int n)
{
    int t = blockIdx.x * blockDim.x + threadIdx.x;
    if (t < n) dst[t] = src[t];
}

// ---------------------------------------------------------------------------
// One 3x3 conv layer: 9 tap-GEMMs on mfma_f32_16x16x32_bf16.
// A from LDS (channel-last rows, ISTR bytes); B double-buffered in registers
// from fragment-packed global Wf (no intra-layer barriers).
// MODE 0: bf16 -> outOff;  MODE 1: f32 -> Y;  MODE 2: Y += o, Z = bf16(Y).
// ---------------------------------------------------------------------------
template <int NIN, int NOUT, int KB, int ISTR, int OSTR, int PMAX, bool SAMEP, int MODE>
__device__ __forceinline__ void conv_mfma(char* sm, int inOff, int outOff,
                                          const bf16* __restrict__ Wl,
                                          const float* __restrict__ bnl)
{
    const int tid = threadIdx.x;
    const int wv = tid >> 6, lane = tid & 63;
    const int r = lane & 15, kg = lane >> 4;
    constexpr int NPIX = NOUT * NOUT;
    constexpr int NMT = (NPIX + 15) / 16;

    __syncthreads();   // input buffer ready (prev layer stores / gather done)

    int ay[PMAX][2], ax[PMAX][2];
    bool act[PMAX][2];
#pragma unroll
    for (int pp = 0; pp < PMAX; ++pp)
#pragma unroll
        for (int mm = 0; mm < 2; ++mm) {
            int mt = (wv + pp * NW) * 2 + mm;
            int pix = mt * 16 + r;
            act[pp][mm] = (mt < NMT);
            int cp = pix < NPIX ? pix : NPIX - 1;
            ay[pp][mm] = cp / NOUT;
            ax[pp][mm] = cp % NOUT;
        }

    float invb[5], betb[5];
#pragma unroll
    for (int n = 0; n < 5; ++n) {
        float2 v = ((const float2*)bnl)[n * 16 + r];
        invb[n] = v.x; betb[n] = v.y;
    }

    f32x4 zz = {0.f, 0.f, 0.f, 0.f};
    f32x4 acc[PMAX][2][5];
#pragma unroll
    for (int pp = 0; pp < PMAX; ++pp)
#pragma unroll
        for (int mm = 0; mm < 2; ++mm)
#pragma unroll
            for (int n = 0; n < 5; ++n) acc[pp][mm][n] = zz;

    short8 B0[15], B1[15];

    auto loadB = [&](short8 (&B)[15], int tap) {
#pragma unroll
        for (int ff = 0; ff < 15; ++ff)
            B[ff] = *(const short8*)(Wl + tap * 7680 + ff * 512 + lane * 8);
    };
    auto compute = [&](short8 (&B)[15], int tap) {
        const int dy = tap / 3, dx = tap % 3;
#pragma unroll
        for (int kb = 0; kb < KB; ++kb) {
#pragma unroll
            for (int pp = 0; pp < PMAX; ++pp) {
                if (2 * (wv + pp * NW) >= NMT) continue;
#pragma unroll
                for (int mm = 0; mm < 2; ++mm) {
                    int iy = ay[pp][mm] + dy - (SAMEP ? 1 : 0);
                    int ix = ax[pp][mm] + dx - (SAMEP ? 1 : 0);
                    bool ok = act[pp][mm];
                    if (SAMEP) ok = ok && (unsigned)iy < (unsigned)NIN
                                       && (unsigned)ix < (unsigned)NIN;
                    if (KB == 3 && kb == 2 && lane >= 32) ok = false;  // k>=80
                    short8 af = {0, 0, 0, 0, 0, 0, 0, 0};
                    if (ok)
                        af = *(const short8*)(sm + inOff + (iy * NIN + ix) * ISTR
                                              + kb * 64 + kg * 16);
#pragma unroll
                    for (int n = 0; n < 5; ++n)
                        acc[pp][mm][n] = __builtin_amdgcn_mfma_f32_16x16x32_bf16(
                            af, B[kb * 5 + n], acc[pp][mm][n], 0, 0, 0);
                }
            }
        }
    };

    loadB(B0, 0);
#pragma unroll
    for (int tp = 0; tp < 4; ++tp) {
        loadB(B1, 2 * tp + 1);
        compute(B0, 2 * tp);
        loadB(B0, 2 * tp + 2);
        compute(B1, 2 * tp + 1);
    }
    compute(B0, 8);

    if (MODE == 2) __syncthreads();   // all K-loop reads of Z done before overwrite

#pragma unroll
    for (int pp = 0; pp < PMAX; ++pp) {
#pragma unroll
        for (int mm = 0; mm < 2; ++mm) {
            int mt = (wv + pp * NW) * 2 + mm;
#pragma unroll
            for (int n = 0; n < 5; ++n) {
                int co = n * 16 + r;
#pragma unroll
                for (int j = 0; j < 4; ++j) {
                    int pix = mt * 16 + kg * 4 + j;
                    if (mt < NMT && pix < NPIX) {
                        float o = fmaxf(acc[pp][mm][n][j] * invb[n] + betb[n], 0.f);
                        if (MODE == 0) {
                            *(bf16*)(sm + outOff + pix * OSTR + co * 2) = f2b(o);
                        } else if (MODE == 1) {
                            *(float*)(sm + Y_OFF + pix * 336 + co * 4) = o;
                        } else {
                            float* yp = (float*)(sm + Y_OFF + pix * 336 + co * 4);
                            float nv = *yp + o;
                            *yp = nv;
                            *(bf16*)(sm + Z_OFF + pix * 176 + co * 2) = f2b(nv);
                        }
                    }
                }
            }
        }
    }
}

// ---------------------------------------------------------------------------
__global__ __launch_bounds__(512, 2) void refine_kernel(
    const int* __restrict__ sel,
    const float* __restrict__ hid, const float* __restrict__ pha,
    const bf16* __restrict__ Wf, const float* __restrict__ wlastT,
    const float* __restrict__ bnprep, float* __restrict__ out)
{
    __shared__ __align__(16) char sm[SMEM_SZ];
    const int tid = threadIdx.x;
    const int p = blockIdx.x;
    const int e = sel[p];
    const int b = p >> 9;
    const int pi = e >> 6, pj = e & 63;

    // ---- gather X[pix 24x24][32ch] bf16 (stride 112B); c-outer for coalescing
    const int r0 = pi * 16 - 4, c0 = pj * 16 - 4;
    for (int t = tid; t < 32 * 576; t += 512) {
        int c = t / 576, pix = t - c * 576;
        int gr = r0 + pix / 24, gc = c0 + pix % 24;
        float v = 0.f;
        if (c < 31 && (unsigned)gr < 1024u && (unsigned)gc < 1024u)
            v = (c < 30) ? hid[((b * 30 + c) * 1024 + gr) * 1024 + gc]
                         : pha[(b * 1024 + gr) * 1024 + gc];
        *(bf16*)(sm + X_OFF + pix * 112 + c * 2) = f2b(v);
    }
    // conv_mfma's entry __syncthreads covers the gather.

    conv_mfma<24, 22, 1, 112, 176, 2, false, 0>(sm, X_OFF,  A0_OFF, Wf,              bnprep);
    conv_mfma<22, 20, 3, 176, 176, 2, false, 0>(sm, A0_OFF, A1_OFF, Wf + 1 * 69120, bnprep + 160);
    conv_mfma<20, 18, 3, 176, 176, 2, false, 0>(sm, A1_OFF, A2_OFF, Wf + 2 * 69120, bnprep + 320);
    conv_mfma<18, 16, 3, 176, 176, 1, false, 1>(sm, A2_OFF, 0,      Wf + 3 * 69120, bnprep + 480);

    // Y -> Z convert (A2 dead after barrier)
    __syncthreads();
    for (int t = tid; t < 20480; t += 512) {
        int pix = t / 80, co = t - pix * 80;
        float v = *(const float*)(sm + Y_OFF + pix * 336 + co * 4);
        *(bf16*)(sm + Z_OFF + pix * 176 + co * 2) = f2b(v);
    }

    for (int l = 0; l < 7; ++l)
        conv_mfma<16, 16, 3, 176, 176, 1, true, 2>(sm, Z_OFF, Z_OFF,
                                                   Wf + (4 + l) * 69120,
                                                   bnprep + 640 + l * 160);

    // ---- last conv 80->1 SAME from f32 trunk; scatter ----
    __syncthreads();
    if (tid < 256) {
        int y = tid >> 4, x = tid & 15;
        float accv = 0.f;
        const float* Yb = (const float*)(sm + Y_OFF);
#pragma unroll
        for (int tap = 0; tap < 9; ++tap) {
            int iy = y + tap / 3 - 1, ix = x + tap % 3 - 1;
            if ((unsigned)iy >= 16u || (unsigned)ix >= 16u) continue;
            const float* yp = Yb + (iy * 16 + ix) * 84;
            const float* wp = wlastT + tap * 80;
            for (int c = 0; c < 80; c += 4) {
                float4 a  = *(const float4*)(yp + c);
                float4 w4 = *(const float4*)(wp + c);
                accv += a.x * w4.x + a.y * w4.y + a.z * w4.z + a.w * w4.w;
            }
        }
        out[b * 1048576 + (pi * 16 + y) * 1024 + pj * 16 + x] = accv;
    }
}

// ---------------------------------------------------------------------------
extern "C" void kernel_launch(void* const* d_in, const int* in_sizes, int n_in,
                              void* d_out, int out_size, void* d_ws, size_t ws_size,
                              hipStream_t stream)
{
    (void)in_sizes; (void)n_in; (void)out_size; (void)ws_size;
    const float* pha     = (const float*)d_in[0];
    const float* err     = (const float*)d_in[1];
    const float* hid     = (const float*)d_in[2];
    const float* w0      = (const float*)d_in[3];
    const float* bn0     = (const float*)d_in[4];
    const float* w_pre   = (const float*)d_in[5];
    const float* bn_pre  = (const float*)d_in[6];
    const float* w_post  = (const float*)d_in[7];
    const float* bn_post = (const float*)d_in[8];
    const float* w_last  = (const float*)d_in[9];
    float* out = (float*)d_out;

    char* ws = (char*)d_ws;
    bf16*  Wf     = (bf16*)ws;                    // 760320 bf16 = 1,520,640 B
    float* wlastT = (float*)(ws + 1520640);       // 720 f32
    float* bnprep = (float*)(ws + 1523520);       // 1760 f32
    int*   sel    = (int*)(ws + 1530624);         // 1024 int

    hipLaunchKernelGGL(wt_kernel, dim3(2980), dim3(256), 0, stream,
                       w0, w_pre, w_post, w_last, bn0, bn_pre, bn_post,
                       Wf, wlastT, bnprep);
    hipLaunchKernelGGL(topk_kernel, dim3(32), dim3(1024), 0, stream,
                       err, out + 2097152, sel);
    hipLaunchKernelGGL(copy_kernel, dim3(2048), dim3(256), 0, stream,
                       (const uint4*)pha, (uint4*)out, 524288);
    hipLaunchKernelGGL(refine_kernel, dim3(1024), dim3(512), 0, stream,
                       sel, hid, pha, Wf, wlastT, bnprep, out);
}

// Round 6
// 600.395 us; speedup vs baseline: 32.7177x; 1.1503x over previous
//
#include <hip/hip_runtime.h>
#include <hip/hip_bf16.h>
#include <stdint.h>

typedef __hip_bfloat16 bf16;
typedef __attribute__((ext_vector_type(8))) short short8;
typedef __attribute__((ext_vector_type(4))) float f32x4;

__device__ __forceinline__ float b2f(bf16 x) { return __bfloat162float(x); }
__device__ __forceinline__ bf16  f2b(float x) { return __float2bfloat16(x); }

#define NW 8

// ---- LDS region map (bytes) ----
// conv0 : A0w[0..77440) X[77440..114304) B0 dbuf[114304..124544)
// pre1  : A0r[0..77440) A1w[77440..141440) Bp dbuf[141440..151680)
// pre2  : A1r            A2w[0..51840)      Bp dbuf
// pre3  : A2r[0..51840)  Zw[51840..92800)   Bf dbuf[92800..123520)
// post  : Z r/w          Bf dbuf
// final : Yf32[51840..137856), last conv
#define A0_OFF 0
#define X_OFF  77440
#define B0_OFF 114304
#define A1_OFF 77440
#define BP_OFF 141440
#define A2_OFF 0
#define Z_OFF  51840
#define BF_OFF 92800
#define YF_OFF 51840
#define SMEM_SZ 151680

// ---------------------------------------------------------------------------
__device__ __forceinline__ void gload_lds16(const void* g, char* l) {
    __builtin_amdgcn_global_load_lds(
        (const __attribute__((address_space(1))) unsigned int*)g,
        (__attribute__((address_space(3))) unsigned int*)l, 16, 0, 0);
}

// swizzled byte address of 16B-group g in activation row (row stride RSTR bytes)
template <int RSTR>
__device__ __forceinline__ int act_addr(int base, int row, int g) {
    int gs;
    if (RSTR == 64) gs = g ^ ((row >> 2) & 3);
    else gs = (g < 8) ? (g ^ ((row >> 2) & 3)) : (8 + ((g & 1) ^ ((row >> 2) & 1)));
    return base + row * RSTR + gs * 16;
}
// swizzled byte address for a single bf16 channel co in a 160B row
__device__ __forceinline__ int act_addr_ch(int base, int row, int co) {
    int g = co >> 3;
    int gs = (g < 8) ? (g ^ ((row >> 2) & 3)) : (8 + ((g & 1) ^ ((row >> 2) & 1)));
    return base + row * 160 + gs * 16 + (co & 7) * 2;
}

// ---------------------------------------------------------------------------
// Top-k: exact rank, jax tie-break (lower index wins). 32 blocks.
// ---------------------------------------------------------------------------
__global__ __launch_bounds__(1024) void topk_kernel(const float* __restrict__ err,
                                                    float* __restrict__ ref_out,
                                                    int* __restrict__ sel)
{
    __shared__ uint64_t keys[4096];
    const int b = blockIdx.x >> 4, slice = blockIdx.x & 15;
    const float* e = err + b * 4096;
    for (int t = threadIdx.x; t < 4096; t += 1024) {
        uint32_t u = __float_as_uint(e[t]);
        u ^= (u >> 31) ? 0xFFFFFFFFu : 0x80000000u;
        keys[t] = ((uint64_t)u << 32) | (uint32_t)(4095 - t);
    }
    __syncthreads();
    const int cand = slice * 256 + (threadIdx.x >> 2);
    const int part = threadIdx.x & 3;
    const uint64_t mykey = keys[cand];
    int r = 0;
#pragma unroll 8
    for (int j = part * 1024; j < part * 1024 + 1024; ++j)
        r += (keys[j] > mykey) ? 1 : 0;
    r += __shfl_xor(r, 1);
    r += __shfl_xor(r, 2);
    if (part == 0) {
        bool s = (r < 512);
        if (s) sel[b * 512 + r] = cand;
        ref_out[b * 4096 + cand] = (s && e[cand] > 0.f) ? 1.f : 0.f;
    }
}

// ---------------------------------------------------------------------------
// Weight prepack: Wf layout = [l][tap](l==0: [n][lane][8] ; else [kb][n][lane][8])
// element: co=n*16+(lane&15), k=kb*32+(lane>>4)*8+i, zero-padded k>=C_in.
// ---------------------------------------------------------------------------
__global__ void wt_kernel(const float* __restrict__ w0, const float* __restrict__ wpre,
                          const float* __restrict__ wpost, const float* __restrict__ w_last,
                          const float* __restrict__ bn0, const float* __restrict__ bn_pre,
                          const float* __restrict__ bn_post,
                          bf16* __restrict__ Wf, float* __restrict__ wlastT,
                          float* __restrict__ bnprep)
{
    int t = blockIdx.x * blockDim.x + threadIdx.x;
    if (t < 714240) {
        int l, tap, kb, rem;
        if (t < 23040) { l = 0; tap = t / 2560; kb = 0; rem = t % 2560; }
        else {
            int t2 = t - 23040;
            l = 1 + t2 / 69120;
            int r0 = t2 % 69120;
            tap = r0 / 7680;
            int r1 = r0 % 7680;
            kb = r1 / 2560; rem = r1 % 2560;
        }
        int n = rem / 512, r2 = rem % 512, lane = r2 / 8, i = r2 % 8;
        int co = n * 16 + (lane & 15);
        int k  = kb * 32 + (lane >> 4) * 8 + i;
        float v = 0.f;
        if (l == 0)      { if (k < 31) v = w0[(co * 31 + k) * 9 + tap]; }
        else if (l <= 3) { if (k < 80) v = wpre[(((l - 1) * 80 + co) * 80 + k) * 9 + tap]; }
        else             { if (k < 80) v = wpost[(((l - 4) * 80 + co) * 80 + k) * 9 + tap]; }
        Wf[t] = f2b(v);
    } else if (t < 714960) {
        int i = t - 714240; int tap = i / 80, ci = i % 80;
        wlastT[tap * 80 + ci] = w_last[ci * 9 + tap];
    } else if (t < 715840) {
        int i = t - 714960; int l = i / 80, co = i % 80;
        const float* src = (l == 0) ? bn0 : (l <= 3 ? bn_pre + (l - 1) * 320
                                                    : bn_post + (l - 4) * 320);
        float g = src[co], bb = src[80 + co], m = src[160 + co], vv = src[240 + co];
        float inv = g * rsqrtf(vv + 1e-5f);
        bnprep[i * 2]     = inv;
        bnprep[i * 2 + 1] = bb - m * inv;
    }
}

// ---------------------------------------------------------------------------
__global__ void copy_kernel(const uint4* __restrict__ src, uint4* __restrict__ dst, int n)
{
    int t = blockIdx.x * blockDim.x + threadIdx.x;
    if (t < n) dst[t] = src[t];
}

// ---------------------------------------------------------------------------
// One 3x3 conv layer: tap-GEMMs on mfma_f32_16x16x32_bf16, B LDS-staged by
// async DMA, double-buffered, one barrier per step (at body END — race-free
// with 2 slots and depth-1 prefetch).
// MODE 0: bf16 out; MODE 1: Yreg = o, Z store; MODE 2: Yreg += o, Z store.
// ---------------------------------------------------------------------------
template <int NIN, int NOUT, int KB, int PMAX, int SAMEP, int MODE, int KBGRAN,
          int INSTR, int SLOTSZ, int STOREZ>
__device__ __forceinline__ void conv_mfma(char* sm, int inBase, int outBase, int bBase,
                                          const char* __restrict__ Wl,
                                          const float* __restrict__ bnl,
                                          f32x4 (&Yreg)[2][5])
{
    const int tid = threadIdx.x;
    const int wv = tid >> 6, lane = tid & 63;
    const int r = lane & 15, kg = lane >> 4;
    constexpr int NPIX = NOUT * NOUT;
    constexpr int NMT = (NPIX + 15) / 16;
    constexpr int NSTEP = KBGRAN ? 9 * KB : 9;

    int ay[PMAX][2], ax[PMAX][2];
    bool act[PMAX][2];
#pragma unroll
    for (int pp = 0; pp < PMAX; ++pp)
#pragma unroll
        for (int mm = 0; mm < 2; ++mm) {
            int mt = (wv + pp * NW) * 2 + mm;
            int pix = mt * 16 + r;
            act[pp][mm] = (mt < NMT);
            int cp = pix < NPIX ? pix : NPIX - 1;
            ay[pp][mm] = cp / NOUT;
            ax[pp][mm] = cp % NOUT;
        }

    float invb[5], betb[5];
#pragma unroll
    for (int n = 0; n < 5; ++n) {
        float2 v = ((const float2*)bnl)[n * 16 + r];
        invb[n] = v.x; betb[n] = v.y;
    }

    f32x4 zz = {0.f, 0.f, 0.f, 0.f};
    f32x4 acc[PMAX][2][5];
#pragma unroll
    for (int pp = 0; pp < PMAX; ++pp)
#pragma unroll
        for (int mm = 0; mm < 2; ++mm)
#pragma unroll
            for (int n = 0; n < 5; ++n) acc[pp][mm][n] = zz;

    auto stage = [&](int step, int slot) {
        char* dst = sm + bBase + slot * SLOTSZ;
        const char* src = Wl + step * SLOTSZ;
        if (SLOTSZ == 15360) {
            gload_lds16(src + tid * 16, dst + tid * 16);
            if (tid < 448) gload_lds16(src + 8192 + tid * 16, dst + 8192 + tid * 16);
        } else {
            if (tid < 320) gload_lds16(src + tid * 16, dst + tid * 16);
        }
    };

    auto compute1 = [&](int tap, int kb, int slotBase) {
        const int dy = tap / 3, dx = tap % 3;
        short8 bf[5];
#pragma unroll
        for (int n = 0; n < 5; ++n)
            bf[n] = *(const short8*)(sm + slotBase + n * 1024 + lane * 16);
#pragma unroll
        for (int pp = 0; pp < PMAX; ++pp) {
            if (2 * (wv + pp * NW) >= NMT) continue;
#pragma unroll
            for (int mm = 0; mm < 2; ++mm) {
                int iy = ay[pp][mm] + dy - SAMEP;
                int ix = ax[pp][mm] + dx - SAMEP;
                bool ok = act[pp][mm];
                if (SAMEP) ok = ok && (unsigned)iy < (unsigned)NIN
                                   && (unsigned)ix < (unsigned)NIN;
                if (KB == 3 && kb == 2 && kg >= 2) ok = false;   // k >= 80 tail
                short8 af = {0, 0, 0, 0, 0, 0, 0, 0};
                if (ok) {
                    int row = iy * NIN + ix;
                    int g = kb * 4 + kg;
                    af = *(const short8*)(sm + act_addr<INSTR>(inBase, row, g));
                }
#pragma unroll
                for (int n = 0; n < 5; ++n)
                    acc[pp][mm][n] = __builtin_amdgcn_mfma_f32_16x16x32_bf16(
                        af, bf[n], acc[pp][mm][n], 0, 0, 0);
            }
        }
    };

    // prologue: stage step 0, drain, barrier (also covers prev layer's stores)
    stage(0, 0);
    asm volatile("s_waitcnt vmcnt(0)" ::: "memory");
    __syncthreads();

    for (int s = 0; s < NSTEP; ++s) {
        if (s + 1 < NSTEP) stage(s + 1, (s + 1) & 1);
        if (KBGRAN) {
            compute1(s / KB, s % KB, bBase + (s & 1) * SLOTSZ);
        } else {
            int sb = bBase + (s & 1) * SLOTSZ;
#pragma unroll
            for (int kb = 0; kb < KB; ++kb) compute1(s, kb, sb + kb * 5120);
        }
        asm volatile("s_waitcnt vmcnt(0)" ::: "memory");
        __syncthreads();
    }

    // ---- epilogue stores (all waves past final barrier -> safe in-place) ----
#pragma unroll
    for (int pp = 0; pp < PMAX; ++pp) {
#pragma unroll
        for (int mm = 0; mm < 2; ++mm) {
            int mt = (wv + pp * NW) * 2 + mm;
#pragma unroll
            for (int n = 0; n < 5; ++n) {
                int co = n * 16 + r;
#pragma unroll
                for (int j = 0; j < 4; ++j) {
                    int pix = mt * 16 + kg * 4 + j;
                    if (mt < NMT && pix < NPIX) {
                        float o = fmaxf(acc[pp][mm][n][j] * invb[n] + betb[n], 0.f);
                        if (MODE == 0) {
                            *(bf16*)(sm + act_addr_ch(outBase, pix, co)) = f2b(o);
                        } else if (MODE == 1) {
                            Yreg[mm][n][j] = o;
                            *(bf16*)(sm + act_addr_ch(outBase, pix, co)) = f2b(o);
                        } else {
                            float nv = Yreg[mm][n][j] + o;
                            Yreg[mm][n][j] = nv;
                            if (STOREZ)
                                *(bf16*)(sm + act_addr_ch(outBase, pix, co)) = f2b(nv);
                        }
                    }
                }
            }
        }
    }
}

// ---------------------------------------------------------------------------
__global__ __launch_bounds__(512, 2) void refine_kernel(
    const int* __restrict__ sel,
    const float* __restrict__ hid, const float* __restrict__ pha,
    const char* __restrict__ Wf, const float* __restrict__ wlastT,
    const float* __restrict__ bnprep, float* __restrict__ out)
{
    __shared__ __align__(16) char sm[SMEM_SZ];
    const int tid = threadIdx.x;
    const int wv = tid >> 6, lane = tid & 63;
    const int r = lane & 15, kg = lane >> 4;
    const int p = blockIdx.x;
    const int e = sel[p];
    const int b = p >> 9;
    const int pi = e >> 6, pj = e & 63;

    // ---- gather X[576 pix][32ch] bf16, 64B swizzled rows ----
    const int r0 = pi * 16 - 4, c0 = pj * 16 - 4;
    for (int t = tid; t < 32 * 576; t += 512) {
        int c = t / 576, pix = t - c * 576;
        int gr = r0 + pix / 24, gc = c0 + pix % 24;
        float v = 0.f;
        if (c < 31 && (unsigned)gr < 1024u && (unsigned)gc < 1024u)
            v = (c < 30) ? hid[((b * 30 + c) * 1024 + gr) * 1024 + gc]
                         : pha[(b * 1024 + gr) * 1024 + gc];
        int byte = X_OFF + pix * 64 + (((c >> 3) ^ ((pix >> 2) & 3)) << 4) + (c & 7) * 2;
        *(bf16*)(sm + byte) = f2b(v);
    }
    // conv prologue barrier covers the gather.

    f32x4 Yreg[2][5];
    const char* W1 = Wf + 46080;

    conv_mfma<24,22,1,2,0,0,0, 64, 5120,1>(sm, X_OFF,  A0_OFF, B0_OFF, Wf,            bnprep,       Yreg);
    conv_mfma<22,20,3,2,0,0,1,160, 5120,1>(sm, A0_OFF, A1_OFF, BP_OFF, W1,            bnprep + 160, Yreg);
    conv_mfma<20,18,3,2,0,0,1,160, 5120,1>(sm, A1_OFF, A2_OFF, BP_OFF, W1 + 138240,   bnprep + 320, Yreg);
    conv_mfma<18,16,3,1,0,1,0,160,15360,1>(sm, A2_OFF, Z_OFF,  BF_OFF, W1 + 2*138240, bnprep + 480, Yreg);
#pragma unroll 1
    for (int l = 0; l < 6; ++l)
        conv_mfma<16,16,3,1,1,2,0,160,15360,1>(sm, Z_OFF, Z_OFF, BF_OFF,
                                               W1 + (3 + l) * 138240,
                                               bnprep + 640 + l * 160, Yreg);
    conv_mfma<16,16,3,1,1,2,0,160,15360,0>(sm, Z_OFF, Z_OFF, BF_OFF,
                                           W1 + 9 * 138240, bnprep + 1600, Yreg);

    // ---- spill Y trunk (f32) to LDS @YF_OFF, stride 336B ----
#pragma unroll
    for (int mm = 0; mm < 2; ++mm) {
        int mt = 2 * wv + mm;
#pragma unroll
        for (int n = 0; n < 5; ++n) {
            int co = n * 16 + r;
#pragma unroll
            for (int j = 0; j < 4; ++j) {
                int pix = mt * 16 + kg * 4 + j;
                *(float*)(sm + YF_OFF + pix * 336 + co * 4) = Yreg[mm][n][j];
            }
        }
    }
    __syncthreads();

    // ---- last conv 80->1 SAME; 2 threads per pixel ----
    {
        int pix = tid >> 1, half = tid & 1;
        int y = pix >> 4, x = pix & 15;
        float accv = 0.f;
        const float* Yb = (const float*)(sm + YF_OFF);
#pragma unroll
        for (int tap = 0; tap < 9; ++tap) {
            int iy = y + tap / 3 - 1, ix = x + tap % 3 - 1;
            if ((unsigned)iy >= 16u || (unsigned)ix >= 16u) continue;
            const float* yp = Yb + (iy * 16 + ix) * 84;
            const float* wp = wlastT + tap * 80;
            for (int c = half * 40; c < half * 40 + 40; c += 4) {
                float4 a  = *(const float4*)(yp + c);
                float4 w4 = *(const float4*)(wp + c);
                accv += a.x * w4.x + a.y * w4.y + a.z * w4.z + a.w * w4.w;
            }
        }
        accv += __shfl_xor(accv, 1);
        if (half == 0)
            out[b * 1048576 + (pi * 16 + y) * 1024 + pj * 16 + x] = accv;
    }
}

// ---------------------------------------------------------------------------
extern "C" void kernel_launch(void* const* d_in, const int* in_sizes, int n_in,
                              void* d_out, int out_size, void* d_ws, size_t ws_size,
                              hipStream_t stream)
{
    (void)in_sizes; (void)n_in; (void)out_size; (void)ws_size;
    const float* pha     = (const float*)d_in[0];
    const float* err     = (const float*)d_in[1];
    const float* hid     = (const float*)d_in[2];
    const float* w0      = (const float*)d_in[3];
    const float* bn0     = (const float*)d_in[4];
    const float* w_pre   = (const float*)d_in[5];
    const float* bn_pre  = (const float*)d_in[6];
    const float* w_post  = (const float*)d_in[7];
    const float* bn_post = (const float*)d_in[8];
    const float* w_last  = (const float*)d_in[9];
    float* out = (float*)d_out;

    char* ws = (char*)d_ws;
    bf16*  Wf     = (bf16*)ws;                 // 714240 bf16 = 1,428,480 B
    float* wlastT = (float*)(ws + 1428480);    // 720 f32
    float* bnprep = (float*)(ws + 1431424);    // 1760 f32
    int*   sel    = (int*)(ws + 1441792);      // 1024 int

    hipLaunchKernelGGL(wt_kernel, dim3(2797), dim3(256), 0, stream,
                       w0, w_pre, w_post, w_last, bn0, bn_pre, bn_post,
                       Wf, wlastT, bnprep);
    hipLaunchKernelGGL(topk_kernel, dim3(32), dim3(1024), 0, stream,
                       err, out + 2097152, sel);
    hipLaunchKernelGGL(copy_kernel, dim3(2048), dim3(256), 0, stream,
                       (const uint4*)pha, (uint4*)out, 524288);
    hipLaunchKernelGGL(refine_kernel, dim3(1024), dim3(512), 0, stream,
                       sel, hid, pha, (const char*)Wf, wlastT, bnprep, out);
}

// Round 8
// 510.487 us; speedup vs baseline: 38.4801x; 1.1761x over previous
//
#include <hip/hip_runtime.h>
#include <hip/hip_bf16.h>
#include <stdint.h>

typedef __hip_bfloat16 bf16;
typedef __attribute__((ext_vector_type(8))) short short8;
typedef __attribute__((ext_vector_type(4))) float f32x4;

__device__ __forceinline__ bf16 f2b(float x) { return __float2bfloat16(x); }

#define NW 8

// ---- LDS map (bytes) ----
// conv0: A0w[0..77440) X[77440..123520) BS[147840..158080)
// pre1 : A0r A1w[77440..147840) BS
// pre2 : A1r A2w[0..57024) BS
// pre3 : A2r Z18w[57024..114048) BB[114048..146816)
// post : Z18 r/w, BB
// final: Yf32[0..86016), last conv
#define A0_OFF 0
#define X_OFF  77440
#define A1_OFF 77440
#define A2_OFF 0
#define Z_OFF  57024
#define BB_OFF 114048      // 2 x 16384
#define BS_OFF 147840      // 2 x 5120
#define YF_OFF 0
#define SMEM_SZ 158080

__device__ __forceinline__ void gload_lds16(const void* g, char* l) {
    __builtin_amdgcn_global_load_lds(
        (const __attribute__((address_space(1))) unsigned int*)g,
        (__attribute__((address_space(3))) unsigned int*)l, 16, 0, 0);
}

// ---------------------------------------------------------------------------
// Top-k: exact rank, jax tie-break (lower index wins). 32 blocks.
// ---------------------------------------------------------------------------
__global__ __launch_bounds__(1024) void topk_kernel(const float* __restrict__ err,
                                                    float* __restrict__ ref_out,
                                                    int* __restrict__ sel)
{
    __shared__ uint64_t keys[4096];
    const int b = blockIdx.x >> 4, slice = blockIdx.x & 15;
    const float* e = err + b * 4096;
    for (int t = threadIdx.x; t < 4096; t += 1024) {
        uint32_t u = __float_as_uint(e[t]);
        u ^= (u >> 31) ? 0xFFFFFFFFu : 0x80000000u;
        keys[t] = ((uint64_t)u << 32) | (uint32_t)(4095 - t);
    }
    __syncthreads();
    const int cand = slice * 256 + (threadIdx.x >> 2);
    const int part = threadIdx.x & 3;
    const uint64_t mykey = keys[cand];
    int r = 0;
#pragma unroll 8
    for (int j = part * 1024; j < part * 1024 + 1024; ++j)
        r += (keys[j] > mykey) ? 1 : 0;
    r += __shfl_xor(r, 1);
    r += __shfl_xor(r, 2);
    if (part == 0) {
        bool s = (r < 512);
        if (s) sel[b * 512 + r] = cand;
        ref_out[b * 4096 + cand] = (s && e[cand] > 0.f) ? 1.f : 0.f;
    }
}

// ---------------------------------------------------------------------------
// Weight prepack: Wf = [l][tap][kb][n][lane][8] bf16 (l==0 has kb=0 only),
// co=n*16+(lane&15), k=kb*32+(lane>>4)*8+i, ZERO for k>=C_in (maskless inner
// loop relies on this). wlastT[tap][ci] f32; bnprep[l][co][{inv,beta}] f32.
// ---------------------------------------------------------------------------
__global__ void wt_kernel(const float* __restrict__ w0, const float* __restrict__ wpre,
                          const float* __restrict__ wpost, const float* __restrict__ w_last,
                          const float* __restrict__ bn0, const float* __restrict__ bn_pre,
                          const float* __restrict__ bn_post,
                          bf16* __restrict__ Wf, float* __restrict__ wlastT,
                          float* __restrict__ bnprep)
{
    int t = blockIdx.x * blockDim.x + threadIdx.x;
    if (t < 714240) {
        int l, tap, kb, rem;
        if (t < 23040) { l = 0; tap = t / 2560; kb = 0; rem = t % 2560; }
        else {
            int t2 = t - 23040;
            l = 1 + t2 / 69120;
            int r0 = t2 % 69120;
            tap = r0 / 7680;
            int r1 = r0 % 7680;
            kb = r1 / 2560; rem = r1 % 2560;
        }
        int n = rem / 512, r2 = rem % 512, lane = r2 / 8, i = r2 % 8;
        int co = n * 16 + (lane & 15);
        int k  = kb * 32 + (lane >> 4) * 8 + i;
        float v = 0.f;
        if (l == 0)      { if (k < 31) v = w0[(co * 31 + k) * 9 + tap]; }
        else if (l <= 3) { if (k < 80) v = wpre[(((l - 1) * 80 + co) * 80 + k) * 9 + tap]; }
        else             { if (k < 80) v = wpost[(((l - 4) * 80 + co) * 80 + k) * 9 + tap]; }
        Wf[t] = f2b(v);
    } else if (t < 714960) {
        int i = t - 714240; int tap = i / 80, ci = i % 80;
        wlastT[tap * 80 + ci] = w_last[ci * 9 + tap];
    } else if (t < 715840) {
        int i = t - 714960; int l = i / 80, co = i % 80;
        const float* src = (l == 0) ? bn0 : (l <= 3 ? bn_pre + (l - 1) * 320
                                                    : bn_post + (l - 4) * 320);
        float g = src[co], bb = src[80 + co], m = src[160 + co], vv = src[240 + co];
        float inv = g * rsqrtf(vv + 1e-5f);
        bnprep[i * 2]     = inv;
        bnprep[i * 2 + 1] = bb - m * inv;
    }
}

// ---------------------------------------------------------------------------
__global__ void copy_kernel(const uint4* __restrict__ src, uint4* __restrict__ dst, int n)
{
    int t = blockIdx.x * blockDim.x + threadIdx.x;
    if (t < n) dst[t] = src[t];
}

// ---------------------------------------------------------------------------
// One 3x3 conv layer, fully unrolled: immediate-offset ds_reads, maskless
// (zero-padded B kills k-tail/clamped/border reads; Z18 has a zero border).
// B double-buffered (2 slots) via async global_load_lds; stage(s+1) issued at
// body top so DMA flies under compute; __syncthreads() (full drain) per step
// -- the R6-proven synchronization. MODE 0: bf16->out; 1: Yreg=o + Z store;
// 2: Yreg+=o (+ Z store if STOREZ).
// ---------------------------------------------------------------------------
template <int NIN, int NOUT, int KB, int PMAX, int MODE, int ISTR, int OSTR,
          int BIG, int STOREZ>
__device__ __forceinline__ void conv_mfma(char* sm, int inBase, int outBase,
                                          const char* __restrict__ Wl,
                                          const float* __restrict__ bnl,
                                          f32x4 (&Yreg)[2][5])
{
    const int tid = threadIdx.x;
    const int wv = tid >> 6, lane = tid & 63;
    const int r = lane & 15, kg = lane >> 4;
    constexpr int NPIX  = NOUT * NOUT;
    constexpr int NMT   = (NPIX + 15) / 16;
    constexpr int NSTEP = BIG ? 9 : 9 * KB;
    constexpr int SLOT  = BIG ? 16384 : 5120;
    constexpr int BOFF  = BIG ? BB_OFF : BS_OFF;
    constexpr int WSTEP = BIG ? 15360 : 5120;

    int aA[PMAX][2];
    bool act[PMAX][2];
#pragma unroll
    for (int pp = 0; pp < PMAX; ++pp)
#pragma unroll
        for (int mm = 0; mm < 2; ++mm) {
            int mt = (wv + pp * NW) * 2 + mm;
            int pix = mt * 16 + r;
            act[pp][mm] = (mt < NMT);   // wave-uniform
            int cp = pix < NPIX ? pix : NPIX - 1;
            aA[pp][mm] = inBase + ((cp / NOUT) * NIN + cp % NOUT) * ISTR + kg * 16;
        }
    const int vB = BOFF + lane * 16;

    float invb[5], betb[5];
#pragma unroll
    for (int n = 0; n < 5; ++n) {
        float2 v = ((const float2*)bnl)[n * 16 + r];
        invb[n] = v.x; betb[n] = v.y;
    }

    f32x4 zz = {0.f, 0.f, 0.f, 0.f};
    f32x4 acc[PMAX][2][5];
#pragma unroll
    for (int pp = 0; pp < PMAX; ++pp)
#pragma unroll
        for (int mm = 0; mm < 2; ++mm)
#pragma unroll
            for (int n = 0; n < 5; ++n) acc[pp][mm][n] = zz;

    auto stage = [&](int step, int slot) {
        const char* src = Wl + step * WSTEP;
        char* dst = sm + BOFF + slot * SLOT;
        if (BIG) {
            gload_lds16(src + tid * 16, dst + tid * 16);
            gload_lds16(src + 8192 + tid * 16, dst + 8192 + tid * 16);
        } else if (tid < 320) {
            gload_lds16(src + tid * 16, dst + tid * 16);
        }
    };

    auto inner = [&](int dtap, int kb, int slotBase) {
        short8 bf[5];
#pragma unroll
        for (int n = 0; n < 5; ++n)
            bf[n] = *(const short8*)(sm + slotBase + n * 1024 + lane * 16);
#pragma unroll
        for (int pp = 0; pp < PMAX; ++pp)
#pragma unroll
            for (int mm = 0; mm < 2; ++mm) {
                if (!act[pp][mm]) continue;   // wave-uniform skip
                short8 af = *(const short8*)(sm + aA[pp][mm] + dtap * ISTR + kb * 64);
#pragma unroll
                for (int n = 0; n < 5; ++n)
                    acc[pp][mm][n] = __builtin_amdgcn_mfma_f32_16x16x32_bf16(
                        af, bf[n], acc[pp][mm][n], 0, 0, 0);
            }
    };

    // prologue: stage slot0; full drain + barrier (also publishes previous
    // layer's LDS stores and covers stage0 completion)
    stage(0, 0);
    __syncthreads();

#pragma unroll
    for (int s = 0; s < NSTEP; ++s) {
        if (s + 1 < NSTEP) stage(s + 1, (s + 1) & 1);   // DMA flies under compute
        const int tap = BIG ? s : s / KB;
        const int dtap = (tap / 3) * NIN + (tap % 3);
        const int sb = BOFF + (s & 1) * SLOT;
        if (BIG) {
#pragma unroll
            for (int kb = 0; kb < 3; ++kb) inner(dtap, kb, sb + kb * 5120);
        } else {
            inner(dtap, s % KB, sb);
        }
        __syncthreads();   // full drain: stage(s+1) + all ds ops
    }

    // epilogue stores (all waves past final barrier -> in-place safe)
#pragma unroll
    for (int pp = 0; pp < PMAX; ++pp)
#pragma unroll
        for (int mm = 0; mm < 2; ++mm) {
            int mt = (wv + pp * NW) * 2 + mm;
            if (mt < NMT) {
#pragma unroll
                for (int n = 0; n < 5; ++n) {
                    int co = n * 16 + r;
#pragma unroll
                    for (int j = 0; j < 4; ++j) {
                        int pix = mt * 16 + kg * 4 + j;
                        if (pix < NPIX) {
                            float o = fmaxf(acc[pp][mm][n][j] * invb[n] + betb[n], 0.f);
                            if (MODE == 0) {
                                *(bf16*)(sm + outBase + pix * OSTR + co * 2) = f2b(o);
                            } else if (MODE == 1) {
                                Yreg[mm][n][j] = o;
                                int rowb = ((pix >> 4) + 1) * (18 * 176) + ((pix & 15) + 1) * 176;
                                *(bf16*)(sm + outBase + rowb + co * 2) = f2b(o);
                            } else {
                                float nv = Yreg[mm][n][j] + o;
                                Yreg[mm][n][j] = nv;
                                if (STOREZ) {
                                    int rowb = ((pix >> 4) + 1) * (18 * 176) + ((pix & 15) + 1) * 176;
                                    *(bf16*)(sm + outBase + rowb + co * 2) = f2b(nv);
                                }
                            }
                        }
                    }
                }
            }
        }
}

// ---------------------------------------------------------------------------
__global__ __launch_bounds__(512, 2) void refine_kernel(
    const int* __restrict__ sel,
    const float* __restrict__ hid, const float* __restrict__ pha,
    const char* __restrict__ Wf, const float* __restrict__ wlastT,
    const float* __restrict__ bnprep, float* __restrict__ out)
{
    __shared__ __align__(16) char sm[SMEM_SZ];
    const int tid = threadIdx.x;
    const int p = blockIdx.x;
    const int e = sel[p];
    const int b = p >> 9;
    const int pi = e >> 6, pj = e & 63;

    // ---- zero-fill LDS once (pad bytes / stale-data NaN safety) ----
    {
        uint4 z4 = {0u, 0u, 0u, 0u};
        uint4* z = (uint4*)sm;
        for (int t = tid; t < SMEM_SZ / 16; t += 512) z[t] = z4;
    }
    __syncthreads();

    // ---- gather X[576 pix][ch] bf16, 80B rows (ch31 zero) ----
    const int r0 = pi * 16 - 4, c0 = pj * 16 - 4;
    for (int t = tid; t < 32 * 576; t += 512) {
        int c = t / 576, pix = t - c * 576;
        int gr = r0 + pix / 24, gc = c0 + pix % 24;
        float v = 0.f;
        if (c < 31 && (unsigned)gr < 1024u && (unsigned)gc < 1024u)
            v = (c < 30) ? hid[((b * 30 + c) * 1024 + gr) * 1024 + gc]
                         : pha[(b * 1024 + gr) * 1024 + gc];
        *(bf16*)(sm + X_OFF + pix * 80 + c * 2) = f2b(v);
    }
    // conv0 prologue __syncthreads covers the gather.

    f32x4 Yreg[2][5];

    conv_mfma<24,22,1,2,0, 80,160,0,1>(sm, X_OFF,  A0_OFF, Wf,                    bnprep,       Yreg);
    conv_mfma<22,20,3,2,0,160,176,0,1>(sm, A0_OFF, A1_OFF, Wf + 46080,            bnprep + 160, Yreg);
    conv_mfma<20,18,3,2,0,176,176,0,1>(sm, A1_OFF, A2_OFF, Wf + 46080 + 138240,   bnprep + 320, Yreg);
    conv_mfma<18,16,3,1,1,176,176,1,1>(sm, A2_OFF, Z_OFF,  Wf + 46080 + 2*138240, bnprep + 480, Yreg);

    // ---- zero Z18 border rows (68 rows x 176B); disjoint from interior ----
    for (int t = tid; t < 68 * 44; t += 512) {
        int idx = t / 44, w = t - idx * 44;
        int row;
        if (idx < 18) row = idx;                         // y = 0
        else if (idx < 36) row = 306 + (idx - 18);       // y = 17
        else { int k = idx - 36; row = (1 + (k >> 1)) * 18 + ((k & 1) ? 17 : 0); }
        *(uint32_t*)(sm + Z_OFF + row * 176 + w * 4) = 0u;
    }
    // post-0 prologue __syncthreads covers border stores.

#pragma unroll 1
    for (int l = 0; l < 6; ++l)
        conv_mfma<18,16,3,1,2,176,176,1,1>(sm, Z_OFF, Z_OFF,
                                           Wf + 46080 + (3 + l) * 138240,
                                           bnprep + 640 + l * 160, Yreg);
    conv_mfma<18,16,3,1,2,176,176,1,0>(sm, Z_OFF, Z_OFF,
                                       Wf + 46080 + 9 * 138240, bnprep + 1600, Yreg);

    // ---- spill Y trunk (f32, stride 336B) over dead A2/Z region ----
    {
        const int wv = tid >> 6, lane = tid & 63;
        const int r = lane & 15, kg = lane >> 4;
#pragma unroll
        for (int mm = 0; mm < 2; ++mm) {
            int mt = 2 * wv + mm;
#pragma unroll
            for (int n = 0; n < 5; ++n) {
                int co = n * 16 + r;
#pragma unroll
                for (int j = 0; j < 4; ++j) {
                    int pix = mt * 16 + kg * 4 + j;
                    *(float*)(sm + YF_OFF + pix * 336 + co * 4) = Yreg[mm][n][j];
                }
            }
        }
    }
    __syncthreads();

    // ---- last conv 80->1 SAME; 2 threads per pixel ----
    {
        int pix = tid >> 1, half = tid & 1;
        int y = pix >> 4, x = pix & 15;
        float accv = 0.f;
        const float* Yb = (const float*)(sm + YF_OFF);
#pragma unroll
        for (int tap = 0; tap < 9; ++tap) {
            int iy = y + tap / 3 - 1, ix = x + tap % 3 - 1;
            if ((unsigned)iy >= 16u || (unsigned)ix >= 16u) continue;
            const float* yp = Yb + (iy * 16 + ix) * 84;
            const float* wp = wlastT + tap * 80;
            for (int c = half * 40; c < half * 40 + 40; c += 4) {
                float4 a  = *(const float4*)(yp + c);
                float4 w4 = *(const float4*)(wp + c);
                accv += a.x * w4.x + a.y * w4.y + a.z * w4.z + a.w * w4.w;
            }
        }
        accv += __shfl_xor(accv, 1);
        if (half == 0)
            out[b * 1048576 + (pi * 16 + y) * 1024 + pj * 16 + x] = accv;
    }
}

// ---------------------------------------------------------------------------
extern "C" void kernel_launch(void* const* d_in, const int* in_sizes, int n_in,
                              void* d_out, int out_size, void* d_ws, size_t ws_size,
                              hipStream_t stream)
{
    (void)in_sizes; (void)n_in; (void)out_size; (void)ws_size;
    const float* pha     = (const float*)d_in[0];
    const float* err     = (const float*)d_in[1];
    const float* hid     = (const float*)d_in[2];
    const float* w0      = (const float*)d_in[3];
    const float* bn0     = (const float*)d_in[4];
    const float* w_pre   = (const float*)d_in[5];
    const float* bn_pre  = (const float*)d_in[6];
    const float* w_post  = (const float*)d_in[7];
    const float* bn_post = (const float*)d_in[8];
    const float* w_last  = (const float*)d_in[9];
    float* out = (float*)d_out;

    char* ws = (char*)d_ws;
    bf16*  Wf     = (bf16*)ws;                 // 714240 bf16 = 1,428,480 B (+1KB stage-overread pad)
    float* wlastT = (float*)(ws + 1429504);    // 720 f32
    float* bnprep = (float*)(ws + 1432384);    // 1760 f32
    int*   sel    = (int*)(ws + 1441792);      // 1024 int

    hipLaunchKernelGGL(wt_kernel, dim3(2797), dim3(256), 0, stream,
                       w0, w_pre, w_post, w_last, bn0, bn_pre, bn_post,
                       Wf, wlastT, bnprep);
    hipLaunchKernelGGL(topk_kernel, dim3(32), dim3(1024), 0, stream,
                       err, out + 2097152, sel);
    hipLaunchKernelGGL(copy_kernel, dim3(2048), dim3(256), 0, stream,
                       (const uint4*)pha, (uint4*)out, 524288);
    hipLaunchKernelGGL(refine_kernel, dim3(1024), dim3(512), 0, stream,
                       sel, hid, pha, (const char*)Wf, wlastT, bnprep, out);
}